// Round 8
// baseline (272.973 us; speedup 1.0000x reference)
//
#include <hip/hip_runtime.h>
#include <hip/hip_bf16.h>
#include <math.h>

#define BB 1024     // batch
#define LL 50       // sequence length
#define DD 256      // embedding dim
#define TWO_D 512
#define NN 40000    // nodes
#define DEG 12      // neighbors per node (adj_rows = repeat(arange(N), DEG))
#define NITER 50    // entmax bisect iterations

typedef __attribute__((ext_vector_type(8))) short short8;
typedef __attribute__((ext_vector_type(4))) float floatx4;

__device__ __forceinline__ float wave_sum64(float v) {
#pragma unroll
    for (int off = 32; off > 0; off >>= 1) v += __shfl_xor(v, off, 64);
    return v;
}
__device__ __forceinline__ float wave_max64(float v) {
#pragma unroll
    for (int off = 32; off > 0; off >>= 1) v = fmaxf(v, __shfl_xor(v, off, 64));
    return v;
}
__device__ __forceinline__ float bf2f(ushort u) {
    union { unsigned int i; float f; } c; c.i = ((unsigned int)u) << 16; return c.f;
}
__device__ __forceinline__ ushort f2bf(float f) {
    __hip_bfloat16 h = __float2bfloat16(f);
    return *(ushort*)&h;
}
__device__ __forceinline__ float hw_exp2(float x) { return __builtin_amdgcn_exp2f(x); }
__device__ __forceinline__ float hw_log2(float x) { return __builtin_amdgcn_logf(x); }

// ---------------- L1 mega: emb->bf16 | w1 transpose | target GEMV ----------
// bid [0,10000): ebf = bf16(item_emb)
// bid [10000,10064): w1t[n][k] = bf16(at_w1[k][n]), k0=(bid-10000)*4
// bid [10064,10320): te[b,:] = tgt[b,:]@wf_w^T + wf_b, b0=(bid-10064)*4
__global__ __launch_bounds__(256) void k_mega1(
    const float* __restrict__ emb, ushort* __restrict__ ebf,
    const float* __restrict__ at_w1, ushort* __restrict__ w1t,
    const float* __restrict__ tgt, const float* __restrict__ wf_w,
    const float* __restrict__ wf_b, float* __restrict__ te)
{
    __shared__ __align__(16) char smem[8192];
    int bid = blockIdx.x;
    int tid = threadIdx.x;

    if (bid < 10000) {
        int i = (bid * 256 + tid) * 4;
        float4 v = *(const float4*)(emb + i);
        ushort4 o;
        o.x = f2bf(v.x); o.y = f2bf(v.y); o.z = f2bf(v.z); o.w = f2bf(v.w);
        *(ushort4*)(ebf + i) = o;
    } else if (bid < 10064) {
        ushort (*s)[DD] = (ushort(*)[DD])smem;
        int k0 = (bid - 10000) * 4;
#pragma unroll
        for (int j = 0; j < 4; ++j) s[j][tid] = f2bf(at_w1[(k0 + j) * DD + tid]);
        __syncthreads();
        ushort4 pk;
        pk.x = s[0][tid]; pk.y = s[1][tid]; pk.z = s[2][tid]; pk.w = s[3][tid];
        *(ushort4*)(w1t + tid * DD + k0) = pk;
    } else {
        float* x_s = (float*)smem;                    // 4*512 floats = 8 KB
        int b0 = (bid - 10064) * 4;
        for (int i = tid; i < 4 * TWO_D; i += 256) x_s[i] = tgt[b0 * TWO_D + i];
        __syncthreads();
        float bias = wf_b[tid];
        float acc[4] = {bias, bias, bias, bias};
        const float4* w4 = (const float4*)(wf_w + tid * TWO_D);
        for (int kk = 0; kk < TWO_D / 4; ++kk) {
            float4 w = w4[kk];
#pragma unroll
            for (int j = 0; j < 4; ++j) {
                const float* xs = x_s + j * TWO_D + kk * 4;
                acc[j] += xs[0] * w.x + xs[1] * w.y + xs[2] * w.z + xs[3] * w.w;
            }
        }
#pragma unroll
        for (int j = 0; j < 4; ++j) te[(b0 + j) * DD + tid] = acc[j];
    }
}

// ---------------- L2 mega: conv | t2 GEMV + alpha ---------------------------
// bid [0,10000): per-node conv, one wave per node (batched neighbor loads)
// bid [10000,10256): t2[b,:] = te[b,:]@at_w2 + at_bias; alpha[b]
__global__ __launch_bounds__(256) void k_mega2(
    const ushort* __restrict__ ebf, const int* __restrict__ adj_cols,
    const float* __restrict__ adj_vals, ushort* __restrict__ gbf,
    const float* __restrict__ te, const float* __restrict__ at_w2,
    const float* __restrict__ at_bias, const float* __restrict__ aw,
    const float* __restrict__ ab, float* __restrict__ t2,
    float* __restrict__ alpha)
{
    __shared__ float te_s[4][DD];
    int bid = blockIdx.x;
    int tid = threadIdx.x;
    int wv = tid >> 6, lane = tid & 63;

    if (bid < 10000) {
        int n = bid * 4 + wv;
        int colv = 0; float valv = 0.f;
        if (lane < DEG) { colv = adj_cols[n * DEG + lane]; valv = adj_vals[n * DEG + lane]; }
        int cols[DEG]; float vals[DEG];
#pragma unroll
        for (int k = 0; k < DEG; ++k) {
            cols[k] = __shfl(colv, k, 64);
            vals[k] = __shfl(valv, k, 64);
        }
        ushort4 s = *(const ushort4*)(ebf + (size_t)n * DD + lane * 4);
        ushort4 e[DEG];
#pragma unroll
        for (int k = 0; k < DEG; ++k)
            e[k] = *(const ushort4*)(ebf + (size_t)cols[k] * DD + lane * 4);
        float a0 = bf2f(s.x), a1 = bf2f(s.y), a2 = bf2f(s.z), a3 = bf2f(s.w);
#pragma unroll
        for (int k = 0; k < DEG; ++k) {
            float v = vals[k];
            a0 += v * bf2f(e[k].x); a1 += v * bf2f(e[k].y);
            a2 += v * bf2f(e[k].z); a3 += v * bf2f(e[k].w);
        }
        ushort4 o;
        o.x = f2bf(0.5f * a0); o.y = f2bf(0.5f * a1);
        o.z = f2bf(0.5f * a2); o.w = f2bf(0.5f * a3);
        *(ushort4*)(gbf + (size_t)n * DD + lane * 4) = o;
    } else {
        int b0 = (bid - 10000) * 4;
        for (int i = tid; i < 4 * DD; i += 256) te_s[i >> 8][i & 255] = te[b0 * DD + i];
        __syncthreads();
        float bias2 = at_bias[tid];
        float acc2[4] = {bias2, bias2, bias2, bias2};
        for (int k = 0; k < DD; ++k) {
            float w = at_w2[k * DD + tid];
#pragma unroll
            for (int j = 0; j < 4; ++j) acc2[j] += te_s[j][k] * w;
        }
#pragma unroll
        for (int j = 0; j < 4; ++j) t2[(b0 + j) * DD + tid] = acc2[j];

        // alpha: wave wv handles batch b0+wv
        float s = te_s[wv][lane] * aw[lane] + te_s[wv][lane + 64] * aw[lane + 64]
                + te_s[wv][lane + 128] * aw[lane + 128] + te_s[wv][lane + 192] * aw[lane + 192];
        s = wave_sum64(s);
        if (lane == 0) {
            float a = 1.f + 1.f / (1.f + expf(-(s + ab[0])));
            if (a == 1.f) a = 1.00001f;
            alpha[b0 + wv] = a;
        }
    }
}

// ---------------- L3: scores via MFMA (R4-proven) ---------------------------
__global__ __launch_bounds__(256) void k_scores_mfma(
    const int* __restrict__ items, const ushort* __restrict__ gbf,
    const ushort* __restrict__ w1t, const float* __restrict__ t2,
    const float* __restrict__ at_w0, float* __restrict__ scores)
{
    __shared__ __align__(16) ushort sA[64 * 72];
    __shared__ __align__(16) ushort sB[256 * 72];
    __shared__ float sred[64][4];
    __shared__ int s_items[64];
    int tid = threadIdx.x;
    int blk = blockIdx.x;
    int lane = tid & 63, wv = tid >> 6;
    int cn = lane & 15, q = lane >> 4;
    int n0 = wv * 64;

    if (tid < 64) s_items[tid] = items[blk * 64 + tid];
    __syncthreads();

    floatx4 acc[4][4];
#pragma unroll
    for (int mt = 0; mt < 4; ++mt)
#pragma unroll
        for (int nt = 0; nt < 4; ++nt)
            acc[mt][nt] = (floatx4){0.f, 0.f, 0.f, 0.f};

#pragma unroll 1
    for (int kc = 0; kc < 4; ++kc) {
#pragma unroll
        for (int it = 0; it < 2; ++it) {
            int i = tid + it * 256;
            int row = i >> 3, seg = i & 7;
            *(uint4*)(sA + row * 72 + seg * 8) =
                *(const uint4*)(gbf + (size_t)s_items[row] * DD + kc * 64 + seg * 8);
        }
#pragma unroll
        for (int it = 0; it < 8; ++it) {
            int i = tid + it * 256;
            int n = i >> 3, seg = i & 7;
            *(uint4*)(sB + n * 72 + seg * 8) =
                *(const uint4*)(w1t + n * DD + kc * 64 + seg * 8);
        }
        __syncthreads();
#pragma unroll
        for (int ks = 0; ks < 2; ++ks) {
            short8 af[4], bfr[4];
#pragma unroll
            for (int mt = 0; mt < 4; ++mt)
                af[mt] = *(const short8*)(sA + (mt * 16 + cn) * 72 + ks * 32 + q * 8);
#pragma unroll
            for (int nt = 0; nt < 4; ++nt)
                bfr[nt] = *(const short8*)(sB + (n0 + nt * 16 + cn) * 72 + ks * 32 + q * 8);
#pragma unroll
            for (int mt = 0; mt < 4; ++mt)
#pragma unroll
                for (int nt = 0; nt < 4; ++nt)
                    acc[mt][nt] = __builtin_amdgcn_mfma_f32_16x16x32_bf16(
                        af[mt], bfr[nt], acc[mt][nt], 0, 0, 0);
        }
        __syncthreads();
    }

    float w0v[4];
#pragma unroll
    for (int nt = 0; nt < 4; ++nt) w0v[nt] = at_w0[n0 + nt * 16 + cn];
#pragma unroll
    for (int mt = 0; mt < 4; ++mt) {
#pragma unroll
        for (int r = 0; r < 4; ++r) {
            int row_in = q * 4 + r;
            int row_g = blk * 64 + mt * 16 + row_in;
            int b = row_g / LL;
            const float* t2b = t2 + b * DD;
            float p = 0.f;
#pragma unroll
            for (int nt = 0; nt < 4; ++nt) {
                int col = n0 + nt * 16 + cn;
                float v = acc[mt][nt][r] + t2b[col];
                p += fmaxf(v, 0.f) * w0v[nt];
            }
            p += __shfl_xor(p, 1, 64);
            p += __shfl_xor(p, 2, 64);
            p += __shfl_xor(p, 4, 64);
            p += __shfl_xor(p, 8, 64);
            if (cn == 0) sred[mt * 16 + row_in][wv] = p;
        }
    }
    __syncthreads();
    if (tid < 64)
        scores[blk * 64 + tid] = sred[tid][0] + sred[tid][1] + sred[tid][2] + sred[tid][3];
}

__device__ __forceinline__ float pw(float z, float invv) {
    return hw_exp2(invv * hw_log2(z));   // z=0 -> exp2(-inf)=0, correct limit
}

// ---------------- L4: entmax + weighted sum + selu + L2 norm (R4-proven) ----
__global__ __launch_bounds__(256) void k_entmax_out(
    const float* __restrict__ scores, const float* __restrict__ alpha,
    const int* __restrict__ items, const ushort* __restrict__ gbf,
    float* __restrict__ out)
{
    __shared__ float attn_s[LL];
    __shared__ int s_it[LL];
    __shared__ float red[4];
    int b = blockIdx.x;
    int tid = threadIdx.x;

    if (tid >= 192 && tid < 192 + LL) s_it[tid - 192] = items[b * LL + (tid - 192)];

    if (tid < 64) {
        int l = tid;
        float a = alpha[b];
        float am1 = a - 1.f;
        float invv = 1.f / am1;
        float x = (l < LL) ? scores[b * LL + l] : -__builtin_inff();
        float Xa = x * am1;

        float mx = wave_max64(Xa);
        float tau_lo = mx - 1.f;
        float tau_hi = mx - hw_exp2(am1 * hw_log2(1.f / (float)LL));

        float f_lo = wave_sum64(pw(fmaxf(Xa - tau_lo, 0.f), invv)) - 1.f;

        float dm = tau_hi - tau_lo;
        float tau_m = tau_lo;
#pragma unroll 1
        for (int it = 0; it < NITER; ++it) {
            dm *= 0.5f;
            tau_m = tau_lo + dm;
            float f_m = wave_sum64(pw(fmaxf(Xa - tau_m, 0.f), invv)) - 1.f;
            if (f_m * f_lo >= 0.f) tau_lo = tau_m;
        }
        float pm = pw(fmaxf(Xa - tau_m, 0.f), invv);
        float s = wave_sum64(pm);
        if (l < LL) attn_s[l] = pm / s;
    }
    __syncthreads();

    int d = tid;
    float c = 0.f;
#pragma unroll
    for (int l = 0; l < LL; ++l)
        c += attn_s[l] * bf2f(gbf[(size_t)s_it[l] * DD + d]);

    const float SC = 1.0507009873554805f;
    const float AL = 1.6732632423543772f;
    c = SC * (c > 0.f ? c : AL * expm1f(c));

    float ss = wave_sum64(c * c);
    int wv = tid >> 6, lane = tid & 63;
    if (lane == 0) red[wv] = ss;
    __syncthreads();
    float tot = red[0] + red[1] + red[2] + red[3];
    out[b * DD + d] = c / sqrtf(tot);
}

extern "C" void kernel_launch(void* const* d_in, const int* in_sizes, int n_in,
                              void* d_out, int out_size, void* d_ws, size_t ws_size,
                              hipStream_t stream) {
    const int*   items     = (const int*)  d_in[0];
    const float* tgt       = (const float*)d_in[3];
    const float* item_emb  = (const float*)d_in[4];
    const int*   adj_cols  = (const int*)  d_in[6];
    const float* adj_vals  = (const float*)d_in[7];
    const float* wf_w      = (const float*)d_in[8];
    const float* wf_b      = (const float*)d_in[9];
    const float* alphaw_w  = (const float*)d_in[10];
    const float* alphaw_b  = (const float*)d_in[11];
    const float* at_w0     = (const float*)d_in[12];
    const float* at_w1     = (const float*)d_in[13];
    const float* at_w2     = (const float*)d_in[14];
    const float* at_bias   = (const float*)d_in[15];

    const size_t SZ_TAB = (size_t)NN * DD * sizeof(ushort);      // 20.48 MB
    char* ws = (char*)d_ws;
    ushort* gbf = (ushort*)ws;   ws += SZ_TAB;
    ushort* ebf = (ushort*)ws;   ws += SZ_TAB;
    ushort* w1t = (ushort*)ws;   ws += (size_t)DD * DD * sizeof(ushort);
    float* te     = (float*)ws;  ws += (size_t)BB * DD * sizeof(float);
    float* t2     = (float*)ws;  ws += (size_t)BB * DD * sizeof(float);
    float* alpha  = (float*)ws;  ws += ((size_t)BB + 32) * sizeof(float);
    float* scores = (float*)ws;  ws += (size_t)BB * LL * sizeof(float);
    float* out    = (float*)d_out;

    k_mega1<<<10320, 256, 0, stream>>>(item_emb, ebf, at_w1, w1t,
                                       tgt, wf_w, wf_b, te);
    k_mega2<<<10256, 256, 0, stream>>>(ebf, adj_cols, adj_vals, gbf,
                                       te, at_w2, at_bias,
                                       alphaw_w, alphaw_b, t2, alpha);
    k_scores_mfma<<<(BB * LL) / 64, 256, 0, stream>>>(items, gbf, w1t, t2, at_w0, scores);
    k_entmax_out<<<BB, 256, 0, stream>>>(scores, alpha, items, gbf, out);
}

// Round 9
// 219.956 us; speedup vs baseline: 1.2410x; 1.2410x over previous
//
#include <hip/hip_runtime.h>
#include <hip/hip_bf16.h>
#include <math.h>

#define BB 1024     // batch
#define LL 50       // sequence length
#define DD 256      // embedding dim
#define TWO_D 512
#define NN 40000    // nodes
#define DEG 12      // neighbors per node (adj_rows = repeat(arange(N), DEG))
#define NITER 50    // entmax bisect iterations

typedef __attribute__((ext_vector_type(8))) short short8;
typedef __attribute__((ext_vector_type(4))) float floatx4;

__device__ __forceinline__ float wave_sum64(float v) {
#pragma unroll
    for (int off = 32; off > 0; off >>= 1) v += __shfl_xor(v, off, 64);
    return v;
}
__device__ __forceinline__ float wave_max64(float v) {
#pragma unroll
    for (int off = 32; off > 0; off >>= 1) v = fmaxf(v, __shfl_xor(v, off, 64));
    return v;
}
__device__ __forceinline__ float bf2f(ushort u) {
    union { unsigned int i; float f; } c; c.i = ((unsigned int)u) << 16; return c.f;
}
__device__ __forceinline__ ushort f2bf(float f) {
    __hip_bfloat16 h = __float2bfloat16(f);
    return *(ushort*)&h;
}
__device__ __forceinline__ float hw_exp2(float x) { return __builtin_amdgcn_exp2f(x); }
__device__ __forceinline__ float hw_log2(float x) { return __builtin_amdgcn_logf(x); }

// K0: ebf = bf16(item_emb)
__global__ __launch_bounds__(256) void k_emb_bf16(
    const float* __restrict__ emb, ushort* __restrict__ ebf)
{
    int i = (blockIdx.x * 256 + threadIdx.x) * 4;
    float4 v = *(const float4*)(emb + i);
    ushort4 o;
    o.x = f2bf(v.x); o.y = f2bf(v.y); o.z = f2bf(v.z); o.w = f2bf(v.w);
    *(ushort4*)(ebf + i) = o;
}

// Kmark: flags[items[i]] = 1. No zero-init needed: any value != 1 (incl. the
// harness 0xAA poison or stale flags) only causes extra conv work, never a
// wrong value -- conv output is identical for every computed node.
__global__ __launch_bounds__(256) void k_mark(
    const int* __restrict__ items, int* __restrict__ flags)
{
    int i = blockIdx.x * 256 + threadIdx.x;
    flags[items[i]] = 1;
}

// K1: per-node conv, one wave per node; skip nodes not referenced by items.
// 12 neighbor rows as independent in-flight loads.
__global__ __launch_bounds__(256) void k_conv_dedup(
    const ushort* __restrict__ ebf, const int* __restrict__ adj_cols,
    const float* __restrict__ adj_vals, const int* __restrict__ flags,
    ushort* __restrict__ gbf)
{
    int wv = threadIdx.x >> 6, lane = threadIdx.x & 63;
    int n = blockIdx.x * 4 + wv;
    if (flags[n] != 1) return;   // wave-uniform early exit (~28% of nodes unused)
    int colv = 0; float valv = 0.f;
    if (lane < DEG) { colv = adj_cols[n * DEG + lane]; valv = adj_vals[n * DEG + lane]; }
    int cols[DEG]; float vals[DEG];
#pragma unroll
    for (int k = 0; k < DEG; ++k) {
        cols[k] = __shfl(colv, k, 64);
        vals[k] = __shfl(valv, k, 64);
    }
    ushort4 s = *(const ushort4*)(ebf + (size_t)n * DD + lane * 4);
    ushort4 e[DEG];
#pragma unroll
    for (int k = 0; k < DEG; ++k)
        e[k] = *(const ushort4*)(ebf + (size_t)cols[k] * DD + lane * 4);
    float a0 = bf2f(s.x), a1 = bf2f(s.y), a2 = bf2f(s.z), a3 = bf2f(s.w);
#pragma unroll
    for (int k = 0; k < DEG; ++k) {
        float v = vals[k];
        a0 += v * bf2f(e[k].x); a1 += v * bf2f(e[k].y);
        a2 += v * bf2f(e[k].z); a3 += v * bf2f(e[k].w);
    }
    ushort4 o;
    o.x = f2bf(0.5f * a0); o.y = f2bf(0.5f * a1);
    o.z = f2bf(0.5f * a2); o.w = f2bf(0.5f * a3);
    *(ushort4*)(gbf + (size_t)n * DD + lane * 4) = o;
}

// Kprep: w1t[n*256+k] = bf16(at_w1[k*256+n])
__global__ __launch_bounds__(256) void k_prep_w1(
    const float* __restrict__ at_w1, ushort* __restrict__ w1t)
{
    __shared__ ushort s[4][DD];
    int k0 = blockIdx.x * 4;
    int n = threadIdx.x;
#pragma unroll
    for (int j = 0; j < 4; ++j) s[j][n] = f2bf(at_w1[(k0 + j) * DD + n]);
    __syncthreads();
    ushort4 pk;
    pk.x = s[0][n]; pk.y = s[1][n]; pk.z = s[2][n]; pk.w = s[3][n];
    *(ushort4*)(w1t + n * DD + k0) = pk;
}

// K2: te[b,d] = sum_k tgt[b,k]*wf_w[d,k] + wf_b[d]   (4 batch rows per block)
__global__ __launch_bounds__(256) void k_target(
    const float* __restrict__ tgt, const float* __restrict__ wf_w,
    const float* __restrict__ wf_b, float* __restrict__ te)
{
    const int BPB = 4;
    __shared__ float x_s[BPB * TWO_D];
    int b0 = blockIdx.x * BPB;
    int tid = threadIdx.x;
    for (int i = tid; i < BPB * TWO_D; i += 256) x_s[i] = tgt[b0 * TWO_D + i];
    __syncthreads();
    float bias = wf_b[tid];
    float acc[BPB];
#pragma unroll
    for (int j = 0; j < BPB; ++j) acc[j] = bias;
    const float4* w4 = (const float4*)(wf_w + tid * TWO_D);
    for (int kk = 0; kk < TWO_D / 4; ++kk) {
        float4 w = w4[kk];
#pragma unroll
        for (int j = 0; j < BPB; ++j) {
            const float* xs = x_s + j * TWO_D + kk * 4;
            acc[j] += xs[0] * w.x + xs[1] * w.y + xs[2] * w.z + xs[3] * w.w;
        }
    }
#pragma unroll
    for (int j = 0; j < BPB; ++j) te[(b0 + j) * DD + tid] = acc[j];
}

// K2b: t2[b,d] = sum_k te[b,k]*at_w2[k,d] + at_bias[d]  + alpha fold
__global__ __launch_bounds__(256) void k_t2a(
    const float* __restrict__ te, const float* __restrict__ at_w2,
    const float* __restrict__ at_bias, const float* __restrict__ aw,
    const float* __restrict__ ab, float* __restrict__ t2,
    float* __restrict__ alpha)
{
    __shared__ float te_s[4][DD];
    int b0 = blockIdx.x * 4;
    int tid = threadIdx.x;
    int wv = tid >> 6, lane = tid & 63;
    for (int i = tid; i < 4 * DD; i += 256) te_s[i >> 8][i & 255] = te[b0 * DD + i];
    __syncthreads();
    float bias = at_bias[tid];
    float acc[4] = {bias, bias, bias, bias};
    for (int k = 0; k < DD; ++k) {
        float w = at_w2[k * DD + tid];
#pragma unroll
        for (int j = 0; j < 4; ++j) acc[j] += te_s[j][k] * w;
    }
#pragma unroll
    for (int j = 0; j < 4; ++j) t2[(b0 + j) * DD + tid] = acc[j];

    // alpha: wave wv handles batch b0+wv
    float s = te_s[wv][lane] * aw[lane] + te_s[wv][lane + 64] * aw[lane + 64]
            + te_s[wv][lane + 128] * aw[lane + 128] + te_s[wv][lane + 192] * aw[lane + 192];
    s = wave_sum64(s);
    if (lane == 0) {
        float a = 1.f + 1.f / (1.f + expf(-(s + ab[0])));
        if (a == 1.f) a = 1.00001f;
        alpha[b0 + wv] = a;
    }
}

// K3 (MFMA): scores[row] = sum_n relu( (H@W1)[row,n] + t2[b,n] ) * w0[n]
// A rows gathered on the fly: H[row] = gbf[items[row]].  (R4-proven)
__global__ __launch_bounds__(256) void k_scores_mfma(
    const int* __restrict__ items, const ushort* __restrict__ gbf,
    const ushort* __restrict__ w1t, const float* __restrict__ t2,
    const float* __restrict__ at_w0, float* __restrict__ scores)
{
    __shared__ __align__(16) ushort sA[64 * 72];
    __shared__ __align__(16) ushort sB[256 * 72];
    __shared__ float sred[64][4];
    __shared__ int s_items[64];
    int tid = threadIdx.x;
    int blk = blockIdx.x;
    int lane = tid & 63, wv = tid >> 6;
    int cn = lane & 15, q = lane >> 4;
    int n0 = wv * 64;

    if (tid < 64) s_items[tid] = items[blk * 64 + tid];
    __syncthreads();

    floatx4 acc[4][4];
#pragma unroll
    for (int mt = 0; mt < 4; ++mt)
#pragma unroll
        for (int nt = 0; nt < 4; ++nt)
            acc[mt][nt] = (floatx4){0.f, 0.f, 0.f, 0.f};

#pragma unroll 1
    for (int kc = 0; kc < 4; ++kc) {
#pragma unroll
        for (int it = 0; it < 2; ++it) {
            int i = tid + it * 256;
            int row = i >> 3, seg = i & 7;
            *(uint4*)(sA + row * 72 + seg * 8) =
                *(const uint4*)(gbf + (size_t)s_items[row] * DD + kc * 64 + seg * 8);
        }
#pragma unroll
        for (int it = 0; it < 8; ++it) {
            int i = tid + it * 256;
            int n = i >> 3, seg = i & 7;
            *(uint4*)(sB + n * 72 + seg * 8) =
                *(const uint4*)(w1t + n * DD + kc * 64 + seg * 8);
        }
        __syncthreads();
#pragma unroll
        for (int ks = 0; ks < 2; ++ks) {
            short8 af[4], bfr[4];
#pragma unroll
            for (int mt = 0; mt < 4; ++mt)
                af[mt] = *(const short8*)(sA + (mt * 16 + cn) * 72 + ks * 32 + q * 8);
#pragma unroll
            for (int nt = 0; nt < 4; ++nt)
                bfr[nt] = *(const short8*)(sB + (n0 + nt * 16 + cn) * 72 + ks * 32 + q * 8);
#pragma unroll
            for (int mt = 0; mt < 4; ++mt)
#pragma unroll
                for (int nt = 0; nt < 4; ++nt)
                    acc[mt][nt] = __builtin_amdgcn_mfma_f32_16x16x32_bf16(
                        af[mt], bfr[nt], acc[mt][nt], 0, 0, 0);
        }
        __syncthreads();
    }

    float w0v[4];
#pragma unroll
    for (int nt = 0; nt < 4; ++nt) w0v[nt] = at_w0[n0 + nt * 16 + cn];
#pragma unroll
    for (int mt = 0; mt < 4; ++mt) {
#pragma unroll
        for (int r = 0; r < 4; ++r) {
            int row_in = q * 4 + r;
            int row_g = blk * 64 + mt * 16 + row_in;
            int b = row_g / LL;
            const float* t2b = t2 + b * DD;
            float p = 0.f;
#pragma unroll
            for (int nt = 0; nt < 4; ++nt) {
                int col = n0 + nt * 16 + cn;
                float v = acc[mt][nt][r] + t2b[col];
                p += fmaxf(v, 0.f) * w0v[nt];
            }
            p += __shfl_xor(p, 1, 64);
            p += __shfl_xor(p, 2, 64);
            p += __shfl_xor(p, 4, 64);
            p += __shfl_xor(p, 8, 64);
            if (cn == 0) sred[mt * 16 + row_in][wv] = p;
        }
    }
    __syncthreads();
    if (tid < 64)
        scores[blk * 64 + tid] = sred[tid][0] + sred[tid][1] + sred[tid][2] + sred[tid][3];
}

__device__ __forceinline__ float pw(float z, float invv) {
    return hw_exp2(invv * hw_log2(z));   // z=0 -> exp2(-inf)=0, correct limit
}

// K4: entmax-bisect over L (wave 0), then c[b,d] = sum_l attn[l]*H[b,l,d],
//     selu, L2-normalize.  (R4-proven)
__global__ __launch_bounds__(256) void k_entmax_out(
    const float* __restrict__ scores, const float* __restrict__ alpha,
    const int* __restrict__ items, const ushort* __restrict__ gbf,
    float* __restrict__ out)
{
    __shared__ float attn_s[LL];
    __shared__ int s_it[LL];
    __shared__ float red[4];
    int b = blockIdx.x;
    int tid = threadIdx.x;

    if (tid >= 192 && tid < 192 + LL) s_it[tid - 192] = items[b * LL + (tid - 192)];

    if (tid < 64) {
        int l = tid;
        float a = alpha[b];
        float am1 = a - 1.f;
        float invv = 1.f / am1;
        float x = (l < LL) ? scores[b * LL + l] : -__builtin_inff();
        float Xa = x * am1;

        float mx = wave_max64(Xa);
        float tau_lo = mx - 1.f;
        float tau_hi = mx - hw_exp2(am1 * hw_log2(1.f / (float)LL));

        float f_lo = wave_sum64(pw(fmaxf(Xa - tau_lo, 0.f), invv)) - 1.f;

        float dm = tau_hi - tau_lo;
        float tau_m = tau_lo;
#pragma unroll 1
        for (int it = 0; it < NITER; ++it) {
            dm *= 0.5f;
            tau_m = tau_lo + dm;
            float f_m = wave_sum64(pw(fmaxf(Xa - tau_m, 0.f), invv)) - 1.f;
            if (f_m * f_lo >= 0.f) tau_lo = tau_m;
        }
        float pm = pw(fmaxf(Xa - tau_m, 0.f), invv);
        float s = wave_sum64(pm);
        if (l < LL) attn_s[l] = pm / s;
    }
    __syncthreads();

    int d = tid;
    float c = 0.f;
#pragma unroll
    for (int l = 0; l < LL; ++l)
        c += attn_s[l] * bf2f(gbf[(size_t)s_it[l] * DD + d]);

    const float SC = 1.0507009873554805f;
    const float AL = 1.6732632423543772f;
    c = SC * (c > 0.f ? c : AL * expm1f(c));

    float ss = wave_sum64(c * c);
    int wv = tid >> 6, lane = tid & 63;
    if (lane == 0) red[wv] = ss;
    __syncthreads();
    float tot = red[0] + red[1] + red[2] + red[3];
    out[b * DD + d] = c / sqrtf(tot);
}

extern "C" void kernel_launch(void* const* d_in, const int* in_sizes, int n_in,
                              void* d_out, int out_size, void* d_ws, size_t ws_size,
                              hipStream_t stream) {
    const int*   items     = (const int*)  d_in[0];
    const float* tgt       = (const float*)d_in[3];
    const float* item_emb  = (const float*)d_in[4];
    const int*   adj_cols  = (const int*)  d_in[6];
    const float* adj_vals  = (const float*)d_in[7];
    const float* wf_w      = (const float*)d_in[8];
    const float* wf_b      = (const float*)d_in[9];
    const float* alphaw_w  = (const float*)d_in[10];
    const float* alphaw_b  = (const float*)d_in[11];
    const float* at_w0     = (const float*)d_in[12];
    const float* at_w1     = (const float*)d_in[13];
    const float* at_w2     = (const float*)d_in[14];
    const float* at_bias   = (const float*)d_in[15];

    const size_t SZ_TAB = (size_t)NN * DD * sizeof(ushort);      // 20.48 MB
    char* ws = (char*)d_ws;
    ushort* gbf = (ushort*)ws;   ws += SZ_TAB;
    ushort* ebf = (ushort*)ws;   ws += SZ_TAB;
    ushort* w1t = (ushort*)ws;   ws += (size_t)DD * DD * sizeof(ushort);
    int*   flags = (int*)ws;     ws += (size_t)NN * sizeof(int);
    float* te     = (float*)ws;  ws += (size_t)BB * DD * sizeof(float);
    float* t2     = (float*)ws;  ws += (size_t)BB * DD * sizeof(float);
    float* alpha  = (float*)ws;  ws += ((size_t)BB + 32) * sizeof(float);
    float* scores = (float*)ws;  ws += (size_t)BB * LL * sizeof(float);
    float* out    = (float*)d_out;

    k_emb_bf16<<<NN * DD / (256 * 4), 256, 0, stream>>>(item_emb, ebf);
    k_mark<<<(BB * LL) / 256, 256, 0, stream>>>(items, flags);
    k_prep_w1<<<DD / 4, 256, 0, stream>>>(at_w1, w1t);
    k_target<<<BB / 4, 256, 0, stream>>>(tgt, wf_w, wf_b, te);
    k_t2a<<<BB / 4, 256, 0, stream>>>(te, at_w2, at_bias, alphaw_w, alphaw_b, t2, alpha);
    k_conv_dedup<<<NN / 4, 256, 0, stream>>>(ebf, adj_cols, adj_vals, flags, gbf);
    k_scores_mfma<<<(BB * LL) / 64, 256, 0, stream>>>(items, gbf, w1t, t2, at_w0, scores);
    k_entmax_out<<<BB, 256, 0, stream>>>(scores, alpha, items, gbf, out);
}

// Round 10
// 219.429 us; speedup vs baseline: 1.2440x; 1.0024x over previous
//
#include <hip/hip_runtime.h>
#include <hip/hip_bf16.h>
#include <math.h>

#define BB 1024     // batch
#define LL 50       // sequence length
#define DD 256      // embedding dim
#define TWO_D 512
#define NN 40000    // nodes
#define DEG 12      // neighbors per node (adj_rows = repeat(arange(N), DEG))
#define NITER 50    // entmax bisect iterations

typedef __attribute__((ext_vector_type(8))) short short8;
typedef __attribute__((ext_vector_type(4))) float floatx4;

__device__ __forceinline__ float wave_sum64(float v) {
#pragma unroll
    for (int off = 32; off > 0; off >>= 1) v += __shfl_xor(v, off, 64);
    return v;
}
__device__ __forceinline__ float wave_max64(float v) {
#pragma unroll
    for (int off = 32; off > 0; off >>= 1) v = fmaxf(v, __shfl_xor(v, off, 64));
    return v;
}
__device__ __forceinline__ float bf2f(ushort u) {
    union { unsigned int i; float f; } c; c.i = ((unsigned int)u) << 16; return c.f;
}
__device__ __forceinline__ ushort f2bf(float f) {
    __hip_bfloat16 h = __float2bfloat16(f);
    return *(ushort*)&h;
}
__device__ __forceinline__ float hw_exp2(float x) { return __builtin_amdgcn_exp2f(x); }
__device__ __forceinline__ float hw_log2(float x) { return __builtin_amdgcn_logf(x); }

// K0: ebf = bf16(item_emb)
__global__ __launch_bounds__(256) void k_emb_bf16(
    const float* __restrict__ emb, ushort* __restrict__ ebf)
{
    int i = (blockIdx.x * 256 + threadIdx.x) * 4;
    float4 v = *(const float4*)(emb + i);
    ushort4 o;
    o.x = f2bf(v.x); o.y = f2bf(v.y); o.z = f2bf(v.z); o.w = f2bf(v.w);
    *(ushort4*)(ebf + i) = o;
}

// Kmark: flags[items[i]] = 1. No zero-init needed (poison != 1 only causes
// extra conv work, never wrong values).
__global__ __launch_bounds__(256) void k_mark(
    const int* __restrict__ items, int* __restrict__ flags)
{
    int i = blockIdx.x * 256 + threadIdx.x;
    flags[items[i]] = 1;
}

// K1: per-node conv, one wave per node; skip unreferenced nodes.
__global__ __launch_bounds__(256) void k_conv_dedup(
    const ushort* __restrict__ ebf, const int* __restrict__ adj_cols,
    const float* __restrict__ adj_vals, const int* __restrict__ flags,
    ushort* __restrict__ gbf)
{
    int wv = threadIdx.x >> 6, lane = threadIdx.x & 63;
    int n = blockIdx.x * 4 + wv;
    if (flags[n] != 1) return;
    int colv = 0; float valv = 0.f;
    if (lane < DEG) { colv = adj_cols[n * DEG + lane]; valv = adj_vals[n * DEG + lane]; }
    int cols[DEG]; float vals[DEG];
#pragma unroll
    for (int k = 0; k < DEG; ++k) {
        cols[k] = __shfl(colv, k, 64);
        vals[k] = __shfl(valv, k, 64);
    }
    ushort4 s = *(const ushort4*)(ebf + (size_t)n * DD + lane * 4);
    ushort4 e[DEG];
#pragma unroll
    for (int k = 0; k < DEG; ++k)
        e[k] = *(const ushort4*)(ebf + (size_t)cols[k] * DD + lane * 4);
    float a0 = bf2f(s.x), a1 = bf2f(s.y), a2 = bf2f(s.z), a3 = bf2f(s.w);
#pragma unroll
    for (int k = 0; k < DEG; ++k) {
        float v = vals[k];
        a0 += v * bf2f(e[k].x); a1 += v * bf2f(e[k].y);
        a2 += v * bf2f(e[k].z); a3 += v * bf2f(e[k].w);
    }
    ushort4 o;
    o.x = f2bf(0.5f * a0); o.y = f2bf(0.5f * a1);
    o.z = f2bf(0.5f * a2); o.w = f2bf(0.5f * a3);
    *(ushort4*)(gbf + (size_t)n * DD + lane * 4) = o;
}

// Kprep: w1t[n*256+k] = bf16(at_w1[k*256+n])
__global__ __launch_bounds__(256) void k_prep_w1(
    const float* __restrict__ at_w1, ushort* __restrict__ w1t)
{
    __shared__ ushort s[4][DD];
    int k0 = blockIdx.x * 4;
    int n = threadIdx.x;
#pragma unroll
    for (int j = 0; j < 4; ++j) s[j][n] = f2bf(at_w1[(k0 + j) * DD + n]);
    __syncthreads();
    ushort4 pk;
    pk.x = s[0][n]; pk.y = s[1][n]; pk.z = s[2][n]; pk.w = s[3][n];
    *(ushort4*)(w1t + n * DD + k0) = pk;
}

// K2: te[b,d] = sum_k tgt[b,k]*wf_w[d,k] + wf_b[d]   (4 batch rows per block)
__global__ __launch_bounds__(256) void k_target(
    const float* __restrict__ tgt, const float* __restrict__ wf_w,
    const float* __restrict__ wf_b, float* __restrict__ te)
{
    const int BPB = 4;
    __shared__ float x_s[BPB * TWO_D];
    int b0 = blockIdx.x * BPB;
    int tid = threadIdx.x;
    for (int i = tid; i < BPB * TWO_D; i += 256) x_s[i] = tgt[b0 * TWO_D + i];
    __syncthreads();
    float bias = wf_b[tid];
    float acc[BPB];
#pragma unroll
    for (int j = 0; j < BPB; ++j) acc[j] = bias;
    const float4* w4 = (const float4*)(wf_w + tid * TWO_D);
    for (int kk = 0; kk < TWO_D / 4; ++kk) {
        float4 w = w4[kk];
#pragma unroll
        for (int j = 0; j < BPB; ++j) {
            const float* xs = x_s + j * TWO_D + kk * 4;
            acc[j] += xs[0] * w.x + xs[1] * w.y + xs[2] * w.z + xs[3] * w.w;
        }
    }
#pragma unroll
    for (int j = 0; j < BPB; ++j) te[(b0 + j) * DD + tid] = acc[j];
}

// K2b: t2[b,d] = sum_k te[b,k]*at_w2[k,d] + at_bias[d]  + alpha fold
__global__ __launch_bounds__(256) void k_t2a(
    const float* __restrict__ te, const float* __restrict__ at_w2,
    const float* __restrict__ at_bias, const float* __restrict__ aw,
    const float* __restrict__ ab, float* __restrict__ t2,
    float* __restrict__ alpha)
{
    __shared__ float te_s[4][DD];
    int b0 = blockIdx.x * 4;
    int tid = threadIdx.x;
    int wv = tid >> 6, lane = tid & 63;
    for (int i = tid; i < 4 * DD; i += 256) te_s[i >> 8][i & 255] = te[b0 * DD + i];
    __syncthreads();
    float bias = at_bias[tid];
    float acc[4] = {bias, bias, bias, bias};
    for (int k = 0; k < DD; ++k) {
        float w = at_w2[k * DD + tid];
#pragma unroll
        for (int j = 0; j < 4; ++j) acc[j] += te_s[j][k] * w;
    }
#pragma unroll
    for (int j = 0; j < 4; ++j) t2[(b0 + j) * DD + tid] = acc[j];

    float s = te_s[wv][lane] * aw[lane] + te_s[wv][lane + 64] * aw[lane + 64]
            + te_s[wv][lane + 128] * aw[lane + 128] + te_s[wv][lane + 192] * aw[lane + 192];
    s = wave_sum64(s);
    if (lane == 0) {
        float a = 1.f + 1.f / (1.f + expf(-(s + ab[0])));
        if (a == 1.f) a = 1.00001f;
        alpha[b0 + wv] = a;
    }
}

// K3 (MFMA, 128-row tile): scores[row] = sum_n relu((H@W1)[row,n]+t2[b,n])*w0[n]
// M=128 gathered rows, N=256 (wave owns 64 cols), K in 4 chunks of 64.
// LDS 55.3 KB -> 2 blocks/CU; per-wave acc 8x4 (128 VGPRs).
__global__ __launch_bounds__(256, 2) void k_scores_mfma(
    const int* __restrict__ items, const ushort* __restrict__ gbf,
    const ushort* __restrict__ w1t, const float* __restrict__ t2,
    const float* __restrict__ at_w0, float* __restrict__ scores)
{
    __shared__ __align__(16) ushort sA[128 * 72];   // 18432 B
    __shared__ __align__(16) ushort sB[256 * 72];   // 36864 B
    __shared__ float sred[128][4];
    __shared__ int s_items[128];
    int tid = threadIdx.x;
    int blk = blockIdx.x;
    int lane = tid & 63, wv = tid >> 6;
    int cn = lane & 15, q = lane >> 4;
    int n0 = wv * 64;

    if (tid < 128) s_items[tid] = items[blk * 128 + tid];
    __syncthreads();

    floatx4 acc[8][4];
#pragma unroll
    for (int mt = 0; mt < 8; ++mt)
#pragma unroll
        for (int nt = 0; nt < 4; ++nt)
            acc[mt][nt] = (floatx4){0.f, 0.f, 0.f, 0.f};

#pragma unroll 1
    for (int kc = 0; kc < 4; ++kc) {
        // stage A chunk: 128 rows x 64 k
#pragma unroll
        for (int it = 0; it < 4; ++it) {
            int i = tid + it * 256;
            int row = i >> 3, seg = i & 7;
            *(uint4*)(sA + row * 72 + seg * 8) =
                *(const uint4*)(gbf + (size_t)s_items[row] * DD + kc * 64 + seg * 8);
        }
        // stage B chunk: 256 n x 64 k
#pragma unroll
        for (int it = 0; it < 8; ++it) {
            int i = tid + it * 256;
            int n = i >> 3, seg = i & 7;
            *(uint4*)(sB + n * 72 + seg * 8) =
                *(const uint4*)(w1t + n * DD + kc * 64 + seg * 8);
        }
        __syncthreads();
#pragma unroll
        for (int ks = 0; ks < 2; ++ks) {
            short8 af[8], bfr[4];
#pragma unroll
            for (int mt = 0; mt < 8; ++mt)
                af[mt] = *(const short8*)(sA + (mt * 16 + cn) * 72 + ks * 32 + q * 8);
#pragma unroll
            for (int nt = 0; nt < 4; ++nt)
                bfr[nt] = *(const short8*)(sB + (n0 + nt * 16 + cn) * 72 + ks * 32 + q * 8);
#pragma unroll
            for (int mt = 0; mt < 8; ++mt)
#pragma unroll
                for (int nt = 0; nt < 4; ++nt)
                    acc[mt][nt] = __builtin_amdgcn_mfma_f32_16x16x32_bf16(
                        af[mt], bfr[nt], acc[mt][nt], 0, 0, 0);
        }
        __syncthreads();
    }

    float w0v[4];
#pragma unroll
    for (int nt = 0; nt < 4; ++nt) w0v[nt] = at_w0[n0 + nt * 16 + cn];
#pragma unroll
    for (int mt = 0; mt < 8; ++mt) {
#pragma unroll
        for (int r = 0; r < 4; ++r) {
            int row_in = q * 4 + r;
            int row = mt * 16 + row_in;
            int b = (blk * 128 + row) / LL;
            const float* t2b = t2 + b * DD;
            float p = 0.f;
#pragma unroll
            for (int nt = 0; nt < 4; ++nt) {
                int col = n0 + nt * 16 + cn;
                float v = acc[mt][nt][r] + t2b[col];
                p += fmaxf(v, 0.f) * w0v[nt];
            }
            p += __shfl_xor(p, 1, 64);
            p += __shfl_xor(p, 2, 64);
            p += __shfl_xor(p, 4, 64);
            p += __shfl_xor(p, 8, 64);
            if (cn == 0) sred[row][wv] = p;
        }
    }
    __syncthreads();
    if (tid < 128)
        scores[blk * 128 + tid] = sred[tid][0] + sred[tid][1] + sred[tid][2] + sred[tid][3];
}

__device__ __forceinline__ float pw(float z, float invv) {
    return hw_exp2(invv * hw_log2(z));   // z=0 -> exp2(-inf)=0, correct limit
}

// K4: entmax-bisect over L (wave 0), then weighted sum + selu + L2 norm.
__global__ __launch_bounds__(256) void k_entmax_out(
    const float* __restrict__ scores, const float* __restrict__ alpha,
    const int* __restrict__ items, const ushort* __restrict__ gbf,
    float* __restrict__ out)
{
    __shared__ float attn_s[LL];
    __shared__ int s_it[LL];
    __shared__ float red[4];
    int b = blockIdx.x;
    int tid = threadIdx.x;

    if (tid >= 192 && tid < 192 + LL) s_it[tid - 192] = items[b * LL + (tid - 192)];

    if (tid < 64) {
        int l = tid;
        float a = alpha[b];
        float am1 = a - 1.f;
        float invv = 1.f / am1;
        float x = (l < LL) ? scores[b * LL + l] : -__builtin_inff();
        float Xa = x * am1;

        float mx = wave_max64(Xa);
        float tau_lo = mx - 1.f;
        float tau_hi = mx - hw_exp2(am1 * hw_log2(1.f / (float)LL));

        float f_lo = wave_sum64(pw(fmaxf(Xa - tau_lo, 0.f), invv)) - 1.f;

        float dm = tau_hi - tau_lo;
        float tau_m = tau_lo;
#pragma unroll 1
        for (int it = 0; it < NITER; ++it) {
            dm *= 0.5f;
            tau_m = tau_lo + dm;
            float f_m = wave_sum64(pw(fmaxf(Xa - tau_m, 0.f), invv)) - 1.f;
            if (f_m * f_lo >= 0.f) tau_lo = tau_m;
        }
        float pm = pw(fmaxf(Xa - tau_m, 0.f), invv);
        float s = wave_sum64(pm);
        if (l < LL) attn_s[l] = pm / s;
    }
    __syncthreads();

    int d = tid;
    float c = 0.f;
#pragma unroll
    for (int l = 0; l < LL; ++l)
        c += attn_s[l] * bf2f(gbf[(size_t)s_it[l] * DD + d]);

    const float SC = 1.0507009873554805f;
    const float AL = 1.6732632423543772f;
    c = SC * (c > 0.f ? c : AL * expm1f(c));

    float ss = wave_sum64(c * c);
    int wv = tid >> 6, lane = tid & 63;
    if (lane == 0) red[wv] = ss;
    __syncthreads();
    float tot = red[0] + red[1] + red[2] + red[3];
    out[b * DD + d] = c / sqrtf(tot);
}

extern "C" void kernel_launch(void* const* d_in, const int* in_sizes, int n_in,
                              void* d_out, int out_size, void* d_ws, size_t ws_size,
                              hipStream_t stream) {
    const int*   items     = (const int*)  d_in[0];
    const float* tgt       = (const float*)d_in[3];
    const float* item_emb  = (const float*)d_in[4];
    const int*   adj_cols  = (const int*)  d_in[6];
    const float* adj_vals  = (const float*)d_in[7];
    const float* wf_w      = (const float*)d_in[8];
    const float* wf_b      = (const float*)d_in[9];
    const float* alphaw_w  = (const float*)d_in[10];
    const float* alphaw_b  = (const float*)d_in[11];
    const float* at_w0     = (const float*)d_in[12];
    const float* at_w1     = (const float*)d_in[13];
    const float* at_w2     = (const float*)d_in[14];
    const float* at_bias   = (const float*)d_in[15];

    const size_t SZ_TAB = (size_t)NN * DD * sizeof(ushort);      // 20.48 MB
    char* ws = (char*)d_ws;
    ushort* gbf = (ushort*)ws;   ws += SZ_TAB;
    ushort* ebf = (ushort*)ws;   ws += SZ_TAB;
    ushort* w1t = (ushort*)ws;   ws += (size_t)DD * DD * sizeof(ushort);
    int*   flags = (int*)ws;     ws += (size_t)NN * sizeof(int);
    float* te     = (float*)ws;  ws += (size_t)BB * DD * sizeof(float);
    float* t2     = (float*)ws;  ws += (size_t)BB * DD * sizeof(float);
    float* alpha  = (float*)ws;  ws += ((size_t)BB + 32) * sizeof(float);
    float* scores = (float*)ws;  ws += (size_t)BB * LL * sizeof(float);
    float* out    = (float*)d_out;

    k_emb_bf16<<<NN * DD / (256 * 4), 256, 0, stream>>>(item_emb, ebf);
    k_mark<<<(BB * LL) / 256, 256, 0, stream>>>(items, flags);
    k_prep_w1<<<DD / 4, 256, 0, stream>>>(at_w1, w1t);
    k_target<<<BB / 4, 256, 0, stream>>>(tgt, wf_w, wf_b, te);
    k_t2a<<<BB / 4, 256, 0, stream>>>(te, at_w2, at_bias, alphaw_w, alphaw_b, t2, alpha);
    k_conv_dedup<<<NN / 4, 256, 0, stream>>>(ebf, adj_cols, adj_vals, flags, gbf);
    k_scores_mfma<<<(BB * LL) / 128, 256, 0, stream>>>(items, gbf, w1t, t2, at_w0, scores);
    k_entmax_out<<<BB, 256, 0, stream>>>(scores, alpha, items, gbf, out);
}

// Round 11
// 213.332 us; speedup vs baseline: 1.2796x; 1.0286x over previous
//
#include <hip/hip_runtime.h>
#include <hip/hip_bf16.h>
#include <math.h>

#define BB 1024     // batch
#define LL 50       // sequence length
#define DD 256      // embedding dim
#define TWO_D 512
#define NN 40000    // nodes
#define DEG 12      // neighbors per node (adj_rows = repeat(arange(N), DEG))
#define NITER 50    // entmax bisect iterations

typedef __attribute__((ext_vector_type(8))) short short8;
typedef __attribute__((ext_vector_type(4))) float floatx4;

__device__ __forceinline__ float wave_sum64(float v) {
#pragma unroll
    for (int off = 32; off > 0; off >>= 1) v += __shfl_xor(v, off, 64);
    return v;
}
__device__ __forceinline__ float wave_max64(float v) {
#pragma unroll
    for (int off = 32; off > 0; off >>= 1) v = fmaxf(v, __shfl_xor(v, off, 64));
    return v;
}
__device__ __forceinline__ float bf2f(ushort u) {
    union { unsigned int i; float f; } c; c.i = ((unsigned int)u) << 16; return c.f;
}
__device__ __forceinline__ ushort f2bf(float f) {
    __hip_bfloat16 h = __float2bfloat16(f);
    return *(ushort*)&h;
}
__device__ __forceinline__ float hw_exp2(float x) { return __builtin_amdgcn_exp2f(x); }
__device__ __forceinline__ float hw_log2(float x) { return __builtin_amdgcn_logf(x); }

// K0: ebf = bf16(item_emb)  |  tail blocks: flags[items[i]] = 1
// (flags need no zero-init: any value != 1, incl. 0xAA poison, only causes
//  extra conv work, never wrong values.)
__global__ __launch_bounds__(256) void k_emb_mark(
    const float* __restrict__ emb, ushort* __restrict__ ebf,
    const int* __restrict__ items, int* __restrict__ flags)
{
    int bid = blockIdx.x;
    int tid = threadIdx.x;
    if (bid < NN * DD / (256 * 4)) {
        int i = (bid * 256 + tid) * 4;
        float4 v = *(const float4*)(emb + i);
        ushort4 o;
        o.x = f2bf(v.x); o.y = f2bf(v.y); o.z = f2bf(v.z); o.w = f2bf(v.w);
        *(ushort4*)(ebf + i) = o;
    } else {
        int i = (bid - NN * DD / (256 * 4)) * 256 + tid;
        flags[items[i]] = 1;
    }
}

// K1: per-node conv, one wave per node; skip unreferenced nodes.
__global__ __launch_bounds__(256) void k_conv_dedup(
    const ushort* __restrict__ ebf, const int* __restrict__ adj_cols,
    const float* __restrict__ adj_vals, const int* __restrict__ flags,
    ushort* __restrict__ gbf)
{
    int wv = threadIdx.x >> 6, lane = threadIdx.x & 63;
    int n = blockIdx.x * 4 + wv;
    if (flags[n] != 1) return;
    int colv = 0; float valv = 0.f;
    if (lane < DEG) { colv = adj_cols[n * DEG + lane]; valv = adj_vals[n * DEG + lane]; }
    int cols[DEG]; float vals[DEG];
#pragma unroll
    for (int k = 0; k < DEG; ++k) {
        cols[k] = __shfl(colv, k, 64);
        vals[k] = __shfl(valv, k, 64);
    }
    ushort4 s = *(const ushort4*)(ebf + (size_t)n * DD + lane * 4);
    ushort4 e[DEG];
#pragma unroll
    for (int k = 0; k < DEG; ++k)
        e[k] = *(const ushort4*)(ebf + (size_t)cols[k] * DD + lane * 4);
    float a0 = bf2f(s.x), a1 = bf2f(s.y), a2 = bf2f(s.z), a3 = bf2f(s.w);
#pragma unroll
    for (int k = 0; k < DEG; ++k) {
        float v = vals[k];
        a0 += v * bf2f(e[k].x); a1 += v * bf2f(e[k].y);
        a2 += v * bf2f(e[k].z); a3 += v * bf2f(e[k].w);
    }
    ushort4 o;
    o.x = f2bf(0.5f * a0); o.y = f2bf(0.5f * a1);
    o.z = f2bf(0.5f * a2); o.w = f2bf(0.5f * a3);
    *(ushort4*)(gbf + (size_t)n * DD + lane * 4) = o;
}

// K2: te[b,d] = tgt[b,:]@wf_w[d,:] + wf_b[d] (4 rows/block)
//     tail blocks: w1t[n][k] = bf16(at_w1[k][n])
__global__ __launch_bounds__(256) void k_target_prep(
    const float* __restrict__ tgt, const float* __restrict__ wf_w,
    const float* __restrict__ wf_b, float* __restrict__ te,
    const float* __restrict__ at_w1, ushort* __restrict__ w1t)
{
    __shared__ float x_s[4 * TWO_D];
    __shared__ ushort s_t[4][DD];
    int bid = blockIdx.x;
    int tid = threadIdx.x;
    if (bid < BB / 4) {
        int b0 = bid * 4;
        for (int i = tid; i < 4 * TWO_D; i += 256) x_s[i] = tgt[b0 * TWO_D + i];
        __syncthreads();
        float bias = wf_b[tid];
        float acc[4] = {bias, bias, bias, bias};
        const float4* w4 = (const float4*)(wf_w + tid * TWO_D);
        for (int kk = 0; kk < TWO_D / 4; ++kk) {
            float4 w = w4[kk];
#pragma unroll
            for (int j = 0; j < 4; ++j) {
                const float* xs = x_s + j * TWO_D + kk * 4;
                acc[j] += xs[0] * w.x + xs[1] * w.y + xs[2] * w.z + xs[3] * w.w;
            }
        }
#pragma unroll
        for (int j = 0; j < 4; ++j) te[(b0 + j) * DD + tid] = acc[j];
    } else {
        int k0 = (bid - BB / 4) * 4;
#pragma unroll
        for (int j = 0; j < 4; ++j) s_t[j][tid] = f2bf(at_w1[(k0 + j) * DD + tid]);
        __syncthreads();
        ushort4 pk;
        pk.x = s_t[0][tid]; pk.y = s_t[1][tid]; pk.z = s_t[2][tid]; pk.w = s_t[3][tid];
        *(ushort4*)(w1t + tid * DD + k0) = pk;
    }
}

// K2b: t2[b,d] = te[b,:]@at_w2[:,d] + at_bias[d]  + alpha fold
__global__ __launch_bounds__(256) void k_t2a(
    const float* __restrict__ te, const float* __restrict__ at_w2,
    const float* __restrict__ at_bias, const float* __restrict__ aw,
    const float* __restrict__ ab, float* __restrict__ t2,
    float* __restrict__ alpha)
{
    __shared__ float te_s[4][DD];
    int b0 = blockIdx.x * 4;
    int tid = threadIdx.x;
    int wv = tid >> 6, lane = tid & 63;
    for (int i = tid; i < 4 * DD; i += 256) te_s[i >> 8][i & 255] = te[b0 * DD + i];
    __syncthreads();
    float bias = at_bias[tid];
    float acc[4] = {bias, bias, bias, bias};
    for (int k = 0; k < DD; ++k) {
        float w = at_w2[k * DD + tid];
#pragma unroll
        for (int j = 0; j < 4; ++j) acc[j] += te_s[j][k] * w;
    }
#pragma unroll
    for (int j = 0; j < 4; ++j) t2[(b0 + j) * DD + tid] = acc[j];

    float s = te_s[wv][lane] * aw[lane] + te_s[wv][lane + 64] * aw[lane + 64]
            + te_s[wv][lane + 128] * aw[lane + 128] + te_s[wv][lane + 192] * aw[lane + 192];
    s = wave_sum64(s);
    if (lane == 0) {
        float a = 1.f + 1.f / (1.f + expf(-(s + ab[0])));
        if (a == 1.f) a = 1.00001f;
        alpha[b0 + wv] = a;
    }
}

// K3 (MFMA, 128-row tile): scores[row] = sum_n relu((H@W1)[row,n]+t2[b,n])*w0[n]
__global__ __launch_bounds__(256, 2) void k_scores_mfma(
    const int* __restrict__ items, const ushort* __restrict__ gbf,
    const ushort* __restrict__ w1t, const float* __restrict__ t2,
    const float* __restrict__ at_w0, float* __restrict__ scores)
{
    __shared__ __align__(16) ushort sA[128 * 72];   // 18432 B
    __shared__ __align__(16) ushort sB[256 * 72];   // 36864 B
    __shared__ float sred[128][4];
    __shared__ int s_items[128];
    int tid = threadIdx.x;
    int blk = blockIdx.x;
    int lane = tid & 63, wv = tid >> 6;
    int cn = lane & 15, q = lane >> 4;
    int n0 = wv * 64;

    if (tid < 128) s_items[tid] = items[blk * 128 + tid];
    __syncthreads();

    floatx4 acc[8][4];
#pragma unroll
    for (int mt = 0; mt < 8; ++mt)
#pragma unroll
        for (int nt = 0; nt < 4; ++nt)
            acc[mt][nt] = (floatx4){0.f, 0.f, 0.f, 0.f};

#pragma unroll 1
    for (int kc = 0; kc < 4; ++kc) {
#pragma unroll
        for (int it = 0; it < 4; ++it) {
            int i = tid + it * 256;
            int row = i >> 3, seg = i & 7;
            *(uint4*)(sA + row * 72 + seg * 8) =
                *(const uint4*)(gbf + (size_t)s_items[row] * DD + kc * 64 + seg * 8);
        }
#pragma unroll
        for (int it = 0; it < 8; ++it) {
            int i = tid + it * 256;
            int n = i >> 3, seg = i & 7;
            *(uint4*)(sB + n * 72 + seg * 8) =
                *(const uint4*)(w1t + n * DD + kc * 64 + seg * 8);
        }
        __syncthreads();
#pragma unroll
        for (int ks = 0; ks < 2; ++ks) {
            short8 af[8], bfr[4];
#pragma unroll
            for (int mt = 0; mt < 8; ++mt)
                af[mt] = *(const short8*)(sA + (mt * 16 + cn) * 72 + ks * 32 + q * 8);
#pragma unroll
            for (int nt = 0; nt < 4; ++nt)
                bfr[nt] = *(const short8*)(sB + (n0 + nt * 16 + cn) * 72 + ks * 32 + q * 8);
#pragma unroll
            for (int mt = 0; mt < 8; ++mt)
#pragma unroll
                for (int nt = 0; nt < 4; ++nt)
                    acc[mt][nt] = __builtin_amdgcn_mfma_f32_16x16x32_bf16(
                        af[mt], bfr[nt], acc[mt][nt], 0, 0, 0);
        }
        __syncthreads();
    }

    float w0v[4];
#pragma unroll
    for (int nt = 0; nt < 4; ++nt) w0v[nt] = at_w0[n0 + nt * 16 + cn];
#pragma unroll
    for (int mt = 0; mt < 8; ++mt) {
#pragma unroll
        for (int r = 0; r < 4; ++r) {
            int row_in = q * 4 + r;
            int row = mt * 16 + row_in;
            int b = (blk * 128 + row) / LL;
            const float* t2b = t2 + b * DD;
            float p = 0.f;
#pragma unroll
            for (int nt = 0; nt < 4; ++nt) {
                int col = n0 + nt * 16 + cn;
                float v = acc[mt][nt][r] + t2b[col];
                p += fmaxf(v, 0.f) * w0v[nt];
            }
            p += __shfl_xor(p, 1, 64);
            p += __shfl_xor(p, 2, 64);
            p += __shfl_xor(p, 4, 64);
            p += __shfl_xor(p, 8, 64);
            if (cn == 0) sred[row][wv] = p;
        }
    }
    __syncthreads();
    if (tid < 128)
        scores[blk * 128 + tid] = sred[tid][0] + sred[tid][1] + sred[tid][2] + sred[tid][3];
}

__device__ __forceinline__ float pw(float z, float invv) {
    return hw_exp2(invv * hw_log2(z));   // z=0 -> exp2(-inf)=0, correct limit
}

// K4: entmax-bisect over L (wave 0), then weighted sum + selu + L2 norm.
__global__ __launch_bounds__(256) void k_entmax_out(
    const float* __restrict__ scores, const float* __restrict__ alpha,
    const int* __restrict__ items, const ushort* __restrict__ gbf,
    float* __restrict__ out)
{
    __shared__ float attn_s[LL];
    __shared__ int s_it[LL];
    __shared__ float red[4];
    int b = blockIdx.x;
    int tid = threadIdx.x;

    if (tid >= 192 && tid < 192 + LL) s_it[tid - 192] = items[b * LL + (tid - 192)];

    if (tid < 64) {
        int l = tid;
        float a = alpha[b];
        float am1 = a - 1.f;
        float invv = 1.f / am1;
        float x = (l < LL) ? scores[b * LL + l] : -__builtin_inff();
        float Xa = x * am1;

        float mx = wave_max64(Xa);
        float tau_lo = mx - 1.f;
        float tau_hi = mx - hw_exp2(am1 * hw_log2(1.f / (float)LL));

        float f_lo = wave_sum64(pw(fmaxf(Xa - tau_lo, 0.f), invv)) - 1.f;

        float dm = tau_hi - tau_lo;
        float tau_m = tau_lo;
#pragma unroll 1
        for (int it = 0; it < NITER; ++it) {
            dm *= 0.5f;
            tau_m = tau_lo + dm;
            float f_m = wave_sum64(pw(fmaxf(Xa - tau_m, 0.f), invv)) - 1.f;
            if (f_m * f_lo >= 0.f) tau_lo = tau_m;
        }
        float pm = pw(fmaxf(Xa - tau_m, 0.f), invv);
        float s = wave_sum64(pm);
        if (l < LL) attn_s[l] = pm / s;
    }
    __syncthreads();

    int d = tid;
    float c = 0.f;
#pragma unroll
    for (int l = 0; l < LL; ++l)
        c += attn_s[l] * bf2f(gbf[(size_t)s_it[l] * DD + d]);

    const float SC = 1.0507009873554805f;
    const float AL = 1.6732632423543772f;
    c = SC * (c > 0.f ? c : AL * expm1f(c));

    float ss = wave_sum64(c * c);
    int wv = tid >> 6, lane = tid & 63;
    if (lane == 0) red[wv] = ss;
    __syncthreads();
    float tot = red[0] + red[1] + red[2] + red[3];
    out[b * DD + d] = c / sqrtf(tot);
}

extern "C" void kernel_launch(void* const* d_in, const int* in_sizes, int n_in,
                              void* d_out, int out_size, void* d_ws, size_t ws_size,
                              hipStream_t stream) {
    const int*   items     = (const int*)  d_in[0];
    const float* tgt       = (const float*)d_in[3];
    const float* item_emb  = (const float*)d_in[4];
    const int*   adj_cols  = (const int*)  d_in[6];
    const float* adj_vals  = (const float*)d_in[7];
    const float* wf_w      = (const float*)d_in[8];
    const float* wf_b      = (const float*)d_in[9];
    const float* alphaw_w  = (const float*)d_in[10];
    const float* alphaw_b  = (const float*)d_in[11];
    const float* at_w0     = (const float*)d_in[12];
    const float* at_w1     = (const float*)d_in[13];
    const float* at_w2     = (const float*)d_in[14];
    const float* at_bias   = (const float*)d_in[15];

    const size_t SZ_TAB = (size_t)NN * DD * sizeof(ushort);      // 20.48 MB
    char* ws = (char*)d_ws;
    ushort* gbf = (ushort*)ws;   ws += SZ_TAB;
    ushort* ebf = (ushort*)ws;   ws += SZ_TAB;
    ushort* w1t = (ushort*)ws;   ws += (size_t)DD * DD * sizeof(ushort);
    int*   flags = (int*)ws;     ws += (size_t)NN * sizeof(int);
    float* te     = (float*)ws;  ws += (size_t)BB * DD * sizeof(float);
    float* t2     = (float*)ws;  ws += (size_t)BB * DD * sizeof(float);
    float* alpha  = (float*)ws;  ws += ((size_t)BB + 32) * sizeof(float);
    float* scores = (float*)ws;  ws += (size_t)BB * LL * sizeof(float);
    float* out    = (float*)d_out;

    k_emb_mark<<<NN * DD / (256 * 4) + (BB * LL) / 256, 256, 0, stream>>>(
        item_emb, ebf, items, flags);
    k_target_prep<<<BB / 4 + DD / 4, 256, 0, stream>>>(
        tgt, wf_w, wf_b, te, at_w1, w1t);
    k_t2a<<<BB / 4, 256, 0, stream>>>(te, at_w2, at_bias, alphaw_w, alphaw_b, t2, alpha);
    k_conv_dedup<<<NN / 4, 256, 0, stream>>>(ebf, adj_cols, adj_vals, flags, gbf);
    k_scores_mfma<<<(BB * LL) / 128, 256, 0, stream>>>(items, gbf, w1t, t2, at_w0, scores);
    k_entmax_out<<<BB, 256, 0, stream>>>(scores, alpha, items, gbf, out);
}